// Round 12
// baseline (486.061 us; speedup 1.0000x reference)
//
#include <hip/hip_runtime.h>
#include <math.h>

// ---- problem dims ----
#define NB 2
#define NSEQ 4096
#define DMODEL 384
#define NH 8
#define DKQ 48
#define DV 48
#define TOPK 128
#define NQ (NB*NSEQ)          // 8192 total query rows

// fp32 combined projection: [q(384) | k(48) | v(48)] = 480 cols
#define QKV_COLS 480
#define C_Q 0
#define C_K 384
#define C_V 432
// fp64 indexer projection Pd[8192][128]: [qi0(32)|qi1(32)|ki(32)|w(2)|pad]
#define IDX_COLS 128
#define P_QI 0
#define P_KI 64
#define P_W  96
#define ATT_SCALE 0.14433756729740643f   // 48^-0.5

typedef double v4d  __attribute__((ext_vector_type(4)));
typedef float  f32x4 __attribute__((ext_vector_type(4)));
typedef short  s16x8 __attribute__((ext_vector_type(8)));

// round-to-nearest-even bf16 split: v ~= hi + lo
__device__ inline void bsplit(float v, unsigned short& h, unsigned short& l) {
    unsigned hb = __float_as_uint(v);
    unsigned short hi = (unsigned short)((hb + 0x7FFFu + ((hb >> 16) & 1u)) >> 16);
    float hf = __uint_as_float(((unsigned)hi) << 16);
    float r = v - hf;
    unsigned rb = __float_as_uint(r);
    unsigned short lo = (unsigned short)((rb + 0x7FFFu + ((rb >> 16) & 1u)) >> 16);
    h = hi; l = lo;
}
__device__ inline unsigned short b16hi(float v) {
    unsigned hb = __float_as_uint(v);
    return (unsigned short)((hb + 0x7FFFu + ((hb >> 16) & 1u)) >> 16);
}

// ------------------------------------------------------------------
// split x into bf16 hi/lo
// ------------------------------------------------------------------
__global__ void k_split(const float* __restrict__ x,
                        unsigned short* __restrict__ xhi, unsigned short* __restrict__ xlo) {
    int i = blockIdx.x * 256 + threadIdx.x;
    if (i < NQ * DMODEL) {
        unsigned short h, l;
        bsplit(x[i], h, l);
        xhi[i] = h; xlo[i] = l;
    }
}

// ------------------------------------------------------------------
// split K|V columns of Y into bf16 hi/lo (MFMA-ready for k_attn)
// ------------------------------------------------------------------
__global__ void k_kvsplit(const float* __restrict__ Y,
                          unsigned short* __restrict__ KVh, unsigned short* __restrict__ KVl) {
    int i = blockIdx.x * 256 + threadIdx.x;
    if (i < NQ * 96) {
        int row = i / 96, c = i % 96;
        unsigned short h, l;
        bsplit(Y[(size_t)row * QKV_COLS + C_K + c], h, l);
        KVh[i] = h; KVl[i] = l;
    }
}

// ------------------------------------------------------------------
// concat + transpose + split weights
// ------------------------------------------------------------------
__global__ void k_concat(const float* __restrict__ wq_idx, const float* __restrict__ wk_idx,
                         const float* __restrict__ ww_idx, const float* __restrict__ wq,
                         const float* __restrict__ wk, const float* __restrict__ wv,
                         const float* __restrict__ wo,
                         unsigned short* __restrict__ WqT_hi, unsigned short* __restrict__ WqT_lo,
                         unsigned short* __restrict__ WoT_hi, unsigned short* __restrict__ WoT_lo,
                         float* __restrict__ Wi_cat) {
    int i = blockIdx.x * 256 + threadIdx.x;
    const int NQK = QKV_COLS * DMODEL;          // 184320
    const int NWO = DMODEL * DMODEL;            // 147456
    if (i < NQK) {
        int n = i / DMODEL, k = i % DMODEL;
        float v;
        if (n < 384)      v = wq[(size_t)k*384 + n];
        else if (n < 432) v = wk[(size_t)k*48 + (n-384)];
        else              v = wv[(size_t)k*48 + (n-432)];
        unsigned short h, l; bsplit(v, h, l);
        WqT_hi[i] = h; WqT_lo[i] = l;
    } else if (i < NQK + NWO) {
        int j = i - NQK;
        int n = j / DMODEL, k = j % DMODEL;
        float v = wo[(size_t)k*384 + n];
        unsigned short h, l; bsplit(v, h, l);
        WoT_hi[j] = h; WoT_lo[j] = l;
    } else if (i < NQK + NWO + DMODEL*IDX_COLS) {
        int j = i - NQK - NWO;
        int d = j / IDX_COLS, c = j % IDX_COLS;
        float v;
        if (c < 64)       v = wq_idx[d*64 + c];
        else if (c < 96)  v = wk_idx[d*32 + (c-64)];
        else if (c < 98)  v = ww_idx[d*2 + (c-96)];
        else              v = 0.f;
        Wi_cat[j] = v;
    }
}

// ------------------------------------------------------------------
// split-bf16 MFMA GEMM: C[M x N] = (Ahi+Alo)[M x 384] @ (Bhi+Blo)^T
// ------------------------------------------------------------------
#define GLDK 40   // shorts per LDS row (32 + 8 pad)
__global__ __launch_bounds__(256) void k_gemm_mfma(
        const unsigned short* __restrict__ Ahi, const unsigned short* __restrict__ Alo,
        const unsigned short* __restrict__ Bhi, const unsigned short* __restrict__ Blo,
        float* __restrict__ C, int N, int ldc) {
    __shared__ unsigned short At[2][128][GLDK];
    __shared__ unsigned short Bt[2][64][GLDK];
    const int t = threadIdx.x;
    const int lane = t & 63, wid = t >> 6;
    const int row0 = blockIdx.y * 128, col0 = blockIdx.x * 64;
    const int ml = lane & 15, kq = lane >> 4;
    const int wm = (wid & 1) * 64, wn = (wid >> 1) * 32;

    // ---- layout calibration probes ----
    unsigned short mv = (unsigned short)(__float_as_uint((float)(ml + 1)) >> 16);
    unsigned short one = 0x3F80;
    s16x8 pa, pb;
    #pragma unroll
    for (int j = 0; j < 8; j++) { pa[j] = (short)mv; pb[j] = (short)one; }
    f32x4 zf = (f32x4){0.f, 0.f, 0.f, 0.f};
    f32x4 rowp = __builtin_amdgcn_mfma_f32_16x16x32_bf16(pa, pb, zf, 0, 0, 0);
    f32x4 colp = __builtin_amdgcn_mfma_f32_16x16x32_bf16(pb, pa, zf, 0, 0, 0);
    int rowm[4], colm[4];
    #pragma unroll
    for (int r = 0; r < 4; r++) {
        rowm[r] = (((int)(rowp[r] * 0.03125f + 0.5f)) - 1) & 15;
        colm[r] = (((int)(colp[r] * 0.03125f + 0.5f)) - 1) & 15;
    }

    f32x4 acc[4][2];
    #pragma unroll
    for (int mt = 0; mt < 4; mt++)
        #pragma unroll
        for (int nt = 0; nt < 2; nt++) acc[mt][nt] = zf;

    for (int k0 = 0; k0 < DMODEL; k0 += 32) {
        #pragma unroll
        for (int i = 0; i < 4; i++) {
            int ch = t + 256*i;
            int arr = ch >> 9, rem = ch & 511;
            int r = rem >> 2, p = rem & 3;
            const unsigned short* src = arr ? Alo : Ahi;
            *(int4*)&At[arr][r][p*8] = *(const int4*)(src + (size_t)(row0 + r)*DMODEL + k0 + p*8);
        }
        #pragma unroll
        for (int i = 0; i < 2; i++) {
            int ch = t + 256*i;
            int arr = ch >> 8, rem = ch & 255;
            int r = rem >> 2, p = rem & 3;
            const unsigned short* src = arr ? Blo : Bhi;
            int gc = col0 + r;
            int4 v = {0, 0, 0, 0};
            if (gc < N) v = *(const int4*)(src + (size_t)gc*DMODEL + k0 + p*8);
            *(int4*)&Bt[arr][r][p*8] = v;
        }
        __syncthreads();
        s16x8 af[4][2], bfr[2][2];
        #pragma unroll
        for (int mt = 0; mt < 4; mt++)
            #pragma unroll
            for (int h = 0; h < 2; h++)
                af[mt][h] = *(const s16x8*)&At[h][wm + mt*16 + ml][kq*8];
        #pragma unroll
        for (int nt = 0; nt < 2; nt++)
            #pragma unroll
            for (int h = 0; h < 2; h++)
                bfr[nt][h] = *(const s16x8*)&Bt[h][wn + nt*16 + ml][kq*8];
        #pragma unroll
        for (int mt = 0; mt < 4; mt++)
            #pragma unroll
            for (int nt = 0; nt < 2; nt++) {
                acc[mt][nt] = __builtin_amdgcn_mfma_f32_16x16x32_bf16(af[mt][0], bfr[nt][0], acc[mt][nt], 0, 0, 0);
                acc[mt][nt] = __builtin_amdgcn_mfma_f32_16x16x32_bf16(af[mt][0], bfr[nt][1], acc[mt][nt], 0, 0, 0);
                acc[mt][nt] = __builtin_amdgcn_mfma_f32_16x16x32_bf16(af[mt][1], bfr[nt][0], acc[mt][nt], 0, 0, 0);
            }
        __syncthreads();
    }
    #pragma unroll
    for (int mt = 0; mt < 4; mt++)
        #pragma unroll
        for (int nt = 0; nt < 2; nt++)
            #pragma unroll
            for (int r = 0; r < 4; r++) {
                int rr = row0 + wm + mt*16 + rowm[r];
                int cc = col0 + wn + nt*16 + colm[r];
                if (cc < N) C[(size_t)rr*ldc + cc] = acc[mt][nt][r];
            }
}

// ------------------------------------------------------------------
// fp64-accumulated indexer projection: Pd[8192][128] = x @ Wi_cat
// ------------------------------------------------------------------
__global__ __launch_bounds__(256) void k_proj64(const float* __restrict__ A,
                                                const float* __restrict__ W,
                                                double* __restrict__ P) {
    __shared__ float At[16][32];
    __shared__ float Bt[16][IDX_COLS];
    const int t  = threadIdx.x;
    const int tx = t & 15;
    const int ty = t >> 4;
    const int row0 = blockIdx.x * 32;
    double acc[2][8] = {};

    for (int k0 = 0; k0 < DMODEL; k0 += 16) {
        if (t < 128) {
            int m = t >> 2, kc = t & 3;
            float4 a = *(const float4*)(A + (size_t)(row0 + m)*DMODEL + k0 + kc*4);
            At[kc*4+0][m] = a.x; At[kc*4+1][m] = a.y;
            At[kc*4+2][m] = a.z; At[kc*4+3][m] = a.w;
        }
        for (int i = 0; i < 2; i++) {
            int lin = t + i*256;
            int kk = lin >> 5, c4 = lin & 31;
            float4 b = *(const float4*)(W + (size_t)(k0+kk)*IDX_COLS + c4*4);
            *(float4*)&Bt[kk][c4*4] = b;
        }
        __syncthreads();
        for (int kk = 0; kk < 16; kk++) {
            float a2[2], b8[8];
            a2[0] = At[kk][ty*2]; a2[1] = At[kk][ty*2+1];
            *(float4*)&b8[0] = *(const float4*)&Bt[kk][tx*8];
            *(float4*)&b8[4] = *(const float4*)&Bt[kk][tx*8+4];
            for (int i = 0; i < 2; i++)
                for (int j = 0; j < 8; j++)
                    acc[i][j] += (double)a2[i] * (double)b8[j];
        }
        __syncthreads();
    }
    for (int i = 0; i < 2; i++)
        for (int j = 0; j < 8; j++)
            P[(size_t)(row0 + ty*2 + i)*IDX_COLS + tx*8 + j] = acc[i][j];
}

// ------------------------------------------------------------------
// fp64 index scores via MFMA f64 16x16x4, self-calibrated C/D layout.
// Emits ONE f32-rounded sortable-u32 key per score. Plain store:
// K32 (134 MB) stays L3-resident for k_topk's reads.
// ------------------------------------------------------------------
__global__ __launch_bounds__(256) void k_score_mfma(const double* __restrict__ P,
                                                    unsigned int* __restrict__ K32,
                                                    int qstart) {
    __shared__ double A0[32][33];
    __shared__ double A1[32][33];
    __shared__ double Bk[32][129];
    __shared__ double wsh[2][32];
    const int t = threadIdx.x;
    const int lane = t & 63;
    const int wid = t >> 6;
    const int g0 = qstart + blockIdx.y * 32;
    const int b  = g0 / NSEQ;
    const int s0 = blockIdx.x * 128;

    for (int i = 0; i < 8; i++) {
        int lin = t + i*256;
        int q = lin >> 6, c = lin & 63;
        double v = P[(size_t)(g0 + q)*IDX_COLS + P_QI + c];
        if (c < 32) A0[c][q] = v; else A1[c-32][q] = v;
    }
    for (int i = 0; i < 16; i++) {
        int lin = t + i*256;
        int s = lin >> 5, c = lin & 31;
        Bk[c][s] = P[(size_t)(b*NSEQ + s0 + s)*IDX_COLS + P_KI + c];
    }
    if (t < 64) wsh[t & 1][t >> 1] = P[(size_t)(g0 + (t >> 1))*IDX_COLS + P_W + (t & 1)];

    const int qw = (wid & 1) * 16;
    const int sw = (wid >> 1) * 64;
    const int ml = lane & 15;
    const int kl = lane >> 4;

    v4d zero = (v4d){0.0, 0.0, 0.0, 0.0};
    v4d rowp = __builtin_amdgcn_mfma_f64_16x16x4f64((double)(ml+1), 1.0, zero, 0, 0, 0);
    v4d colp = __builtin_amdgcn_mfma_f64_16x16x4f64(1.0, (double)(ml+1), zero, 0, 0, 0);
    int rowm[4], colm[4];
    #pragma unroll
    for (int r = 0; r < 4; r++) {
        rowm[r] = (((int)(rowp[r] * 0.25 + 0.5)) - 1) & 15;
        colm[r] = (((int)(colp[r] * 0.25 + 0.5)) - 1) & 15;
    }

    __syncthreads();

    v4d acc0[4], acc1[4];
    #pragma unroll
    for (int st = 0; st < 4; st++) { acc0[st] = zero; acc1[st] = zero; }

    #pragma unroll
    for (int k4 = 0; k4 < 8; k4++) {
        int k = k4*4 + kl;
        double a0 = A0[k][qw + ml];
        double a1 = A1[k][qw + ml];
        #pragma unroll
        for (int st = 0; st < 4; st++) {
            double bb = Bk[k][sw + st*16 + ml];
            acc0[st] = __builtin_amdgcn_mfma_f64_16x16x4f64(a0, bb, acc0[st], 0, 0, 0);
            acc1[st] = __builtin_amdgcn_mfma_f64_16x16x4f64(a1, bb, acc1[st], 0, 0, 0);
        }
    }

    #pragma unroll
    for (int reg = 0; reg < 4; reg++) {
        int q = qw + rowm[reg];
        double w0 = wsh[0][q], w1 = wsh[1][q];
        #pragma unroll
        for (int st = 0; st < 4; st++) {
            double sc = w0 * fmax(acc0[st][reg], 0.0) + w1 * fmax(acc1[st][reg], 0.0);
            size_t oidx = (size_t)(blockIdx.y*32 + q)*NSEQ + s0 + sw + st*16 + colm[reg];
            float sf = (float)sc;
            unsigned int ub = __float_as_uint(sf);
            unsigned int u = (ub & 0x80000000u) ? ~ub : (ub | 0x80000000u);
            K32[oidx] = u;
        }
    }
}

// ------------------------------------------------------------------
// Block-per-query top-128: u32 f32-sortable keys, single-stage.
// (unchanged - proven)
// ------------------------------------------------------------------
__global__ __launch_bounds__(256) void k_topk(const unsigned int* __restrict__ K32,
                                              int* __restrict__ IDX, int qstart) {
    __shared__ unsigned int pool[1024];   // fast: CK[512]|CI[512]; fallback: hist[4][256]
    __shared__ unsigned int wred[4];
    __shared__ unsigned int s_b, s_need, s_flag, s_cnt, s_n;
    unsigned int* CK = pool;
    int* CI = (int*)(pool + 512);
    const int t = threadIdx.x, lane = t & 63;
    const int wid = t >> 6;
    const int q = blockIdx.x;
    const unsigned int* krow = K32 + (size_t)q * NSEQ;
    int* orow = IDX + (size_t)(qstart + q) * TOPK;

    // slot j (0..15) <-> index i = (j>>2)*1024 + t*4 + (j&3)
    unsigned int kr[16];
    #pragma unroll
    for (int jj = 0; jj < 4; jj++) {
        uint4 v = *(const uint4*)(krow + (t*4 + 1024*jj));
        kr[jj*4+0] = v.x; kr[jj*4+1] = v.y; kr[jj*4+2] = v.z; kr[jj*4+3] = v.w;
    }
    unsigned int mymax = kr[0];
    #pragma unroll
    for (int j = 1; j < 16; j++) mymax = kr[j] > mymax ? kr[j] : mymax;
    const unsigned int p16 = mymax >> 16;

    // per-wave bisection: largest Tw with >=32 lane-maxima prefix16 >= Tw
    unsigned int Tw = 0;
    #pragma unroll
    for (int bit = 15; bit >= 0; --bit) {
        unsigned int trial = Tw | (1u << bit);
        if (__popcll(__ballot(p16 >= trial)) >= 32) Tw = trial;
    }
    if (lane == 0) wred[wid] = Tw;
    if (t == 0) { s_cnt = 0; s_n = 0; s_need = TOPK; s_flag = 0; }
    __syncthreads();
    unsigned int T16 = wred[0];
    T16 = wred[1] < T16 ? wred[1] : T16;
    T16 = wred[2] < T16 ? wred[2] : T16;
    T16 = wred[3] < T16 ? wred[3] : T16;

    // compact candidates (prefix16 >= T16), bounded at 512
    #pragma unroll
    for (int j = 0; j < 16; j++) {
        if ((kr[j] >> 16) >= T16) {
            unsigned int pos = atomicAdd(&s_n, 1u);
            if (pos < 512u) { CK[pos] = kr[j]; CI[pos] = (j >> 2)*1024 + t*4 + (j & 3); }
        }
    }
    __syncthreads();
    const unsigned int n = s_n;

    if (n <= 512u) {
        // ---------- FAST PATH: wave 0 exact bisection select ----------
        if (wid == 0) {
            unsigned int ck[8]; int ci[8]; bool cv[8];
            #pragma unroll
            for (int e = 0; e < 8; e++) {
                int id = lane + e*64;
                cv[e] = (unsigned int)id < n;
                ck[e] = cv[e] ? CK[id] : 0u;
                ci[e] = cv[e] ? CI[id] : 0;
            }
            // exact 128th-largest key: largest T with cnt(>=T) >= TOPK
            unsigned int T = 0;
            for (int bit = 31; bit >= 0; --bit) {
                unsigned int trial = T | (1u << bit);
                unsigned int c = 0;
                #pragma unroll
                for (int e = 0; e < 8; e++)
                    c += (unsigned int)__popcll(__ballot(cv[e] && ck[e] >= trial));
                if (c >= (unsigned int)TOPK) T = trial;
            }
            unsigned int G = 0, E = 0;
            #pragma unroll
            for (int e = 0; e < 8; e++) {
                G += (unsigned int)__popcll(__ballot(cv[e] && ck[e] > T));
                E += (unsigned int)__popcll(__ballot(cv[e] && ck[e] == T));
            }
            const unsigned int need = (unsigned int)TOPK - G;
            const unsigned long long ltm = (1ull << lane) - 1ull;

            unsigned int cbase = 0;
            #pragma unroll
            for (int e = 0; e < 8; e++) {              // emit strict-greater
                bool em = cv[e] && ck[e] > T;
                unsigned long long m = __ballot(em);
                if (em) orow[cbase + __popcll(m & ltm)] = ci[e];
                cbase += (unsigned int)__popcll(m);
            }
            if (E == need) {                            // ties exactly fill
                #pragma unroll
                for (int e = 0; e < 8; e++) {
                    bool em = cv[e] && ck[e] == T;
                    unsigned long long m = __ballot(em);
                    if (em) orow[cbase + __popcll(m & ltm)] = ci[e];
                    cbase += (unsigned int)__popcll(m);
                }
            } else {
                // need smallest indices among ==T: max r with cntLE(r) <= need
                unsigned int r = 0;
                for (int bit = 11; bit >= 0; --bit) {
                    unsigned int trial = r | (1u << bit);
                    unsigned int c = 0;
                    #pragma unroll
                    for (int e = 0; e < 8; e++)
                        c += (unsigned int)__popcll(__ballot(cv[e] && ck[e] == T &&
                                 (unsigned int)ci[e] <= trial));
                    if (c <= need) r = trial;
                }
                #pragma unroll
                for (int e = 0; e < 8; e++) {
                    bool em = cv[e] && ck[e] == T && (unsigned int)ci[e] <= r;
                    unsigned long long m = __ballot(em);
                    if (em) orow[cbase + __popcll(m & ltm)] = ci[e];
                    cbase += (unsigned int)__popcll(m);
                }
            }
        }
        return;
    }

    // ---------- FALLBACK (degenerate rows): radix-byte select ----------
    unsigned int amask = 0;
    #pragma unroll
    for (int j = 0; j < 16; j++)
        if ((kr[j] >> 16) >= T16) amask |= (1u << j);

    unsigned int (*hist)[256] = (unsigned int (*)[256])pool;
    auto clearhist = [&]() {
        #pragma unroll
        for (int w = 0; w < 4; w++) hist[w][t] = 0;
        __syncthreads();
    };
    auto decide = [&]() {
        if (wid == 0) {
            unsigned int c[4];
            #pragma unroll
            for (int k2 = 0; k2 < 4; k2++)
                c[k2] = hist[0][lane*4+k2] + hist[1][lane*4+k2]
                      + hist[2][lane*4+k2] + hist[3][lane*4+k2];
            unsigned int run = c[0] + c[1] + c[2] + c[3];
            #pragma unroll
            for (int d2 = 1; d2 < 64; d2 <<= 1) {
                unsigned int v = __shfl_down(run, d2, 64);
                if (lane + d2 < 64) run += v;
            }
            unsigned int need = s_need;
            unsigned int Sb[5];
            Sb[0] = run; Sb[1] = run - c[0]; Sb[2] = Sb[1] - c[1];
            Sb[3] = Sb[2] - c[2]; Sb[4] = Sb[3] - c[3];
            #pragma unroll
            for (int j = 0; j < 4; j++) {
                if (Sb[j] >= need && Sb[j+1] < need) {
                    s_b = (unsigned int)(lane*4 + j);
                    s_need = need - Sb[j+1];
                    s_flag = (need - Sb[j+1] == c[j]) ? 1u : 0u;
                }
            }
        }
        __syncthreads();
    };

    #pragma unroll 1
    for (int level = 0; level < 4; ++level) {
        const int sh = 24 - 8*level;
        clearhist();
        #pragma unroll
        for (int j = 0; j < 16; j++) {
            if ((amask >> j) & 1u)
                atomicAdd(&hist[wid][(kr[j] >> sh) & 255u], 1u);
        }
        __syncthreads();
        decide();
        const unsigned int bstar = s_b;

        if (s_flag) {
            #pragma unroll
            for (int j = 0; j < 16; j++) {
                if (((amask >> j) & 1u) && (((kr[j] >> sh) & 255u) >= bstar))
                    orow[atomicAdd(&s_cnt, 1u)] = (j >> 2)*1024 + t*4 + (j & 3);
            }
            return;
        }
        unsigned int nm = 0;
        #pragma unroll
        for (int j = 0; j < 16; j++) {
            if ((amask >> j) & 1u) {
                unsigned int d = (kr[j] >> sh) & 255u;
                if (d > bstar) orow[atomicAdd(&s_cnt, 1u)] = (j >> 2)*1024 + t*4 + (j & 3);
                else if (d == bstar) nm |= (1u << j);
            }
        }
        amask = nm;
    }

    // full 32-bit ties: lowest indices fill the remaining slots
    const unsigned int needF = s_need;
    unsigned int base = 0;
    #pragma unroll 1
    for (int jj = 0; jj < 4; jj++) {
        unsigned int m4 = (amask >> (jj*4)) & 0xFu;
        unsigned int cnt = __popc(m4);
        unsigned int inc = cnt;
        #pragma unroll
        for (int d2 = 1; d2 < 64; d2 <<= 1) {
            unsigned int v = __shfl_up(inc, d2, 64);
            if (lane >= d2) inc += v;
        }
        if (lane == 63) wred[wid] = inc;
        __syncthreads();
        unsigned int woff = 0;
        for (int w2 = 0; w2 < wid; w2++) woff += wred[w2];
        unsigned int T = wred[0] + wred[1] + wred[2] + wred[3];
        unsigned int p = base + woff + inc - cnt;
        #pragma unroll
        for (int c = 0; c < 4; c++) {
            if ((m4 >> c) & 1u) {
                if (p < needF) orow[atomicAdd(&s_cnt, 1u)] = jj*1024 + t*4 + c;
                p++;
            }
        }
        base += T;
        __syncthreads();
    }
}

// ------------------------------------------------------------------
// Fused attention v4 (MFMA): 512 threads, 8 waves.
//  - gather bf16 K (hi+lo, cols 48..63 zeroed) and V (hi only) from
//    pre-split KVh/KVl; Q bsplit in-kernel (rows 8..15 / cols>=48 zero)
//  - QK: wave w owns key tile w*16; 2 K-steps x 3 split-MFMAs -> S f32
//  - softmax (proven 256-thread pattern) -> probs bf16-hi Ph
//  - PV: waves 0..2 own dd-tiles; A=Ph b128 frags, B=V^T scalar frags,
//    4 MFMAs each; calibrated C layout -> ctx bf16 hi/lo
// ------------------------------------------------------------------
__global__ __launch_bounds__(512) void k_attn(const float* __restrict__ Y,
                                              const unsigned short* __restrict__ KVh,
                                              const unsigned short* __restrict__ KVl,
                                              const int* __restrict__ IDX,
                                              unsigned short* __restrict__ ctx_hi,
                                              unsigned short* __restrict__ ctx_lo) {
    __shared__ unsigned short Kh[TOPK][72];   // 18 KB, cols 48..63 zero, 64..71 pad
    __shared__ unsigned short Kl[TOPK][72];   // 18 KB
    __shared__ unsigned short Vh[TOPK][56];   // 14 KB, row-major V hi
    __shared__ unsigned short Qh[16][72];     // 2.25 KB
    __shared__ unsigned short Ql[16][72];     // 2.25 KB
    __shared__ float Ssc[16][132];            // 8.25 KB logits
    __shared__ unsigned short Ph[16][136];    // 4.25 KB probs bf16-hi
    __shared__ int idxs[TOPK];
    const int g = blockIdx.x;
    const int b = g / NSEQ;
    const int t = threadIdx.x;
    const int lane = t & 63, wid = t >> 6;
    const int ml = lane & 15, kq = lane >> 4;

    // ---- layout calibration probes (proven pattern) ----
    unsigned short mv = b16hi((float)(ml + 1));
    s16x8 cpa, cpb;
    #pragma unroll
    for (int j = 0; j < 8; j++) { cpa[j] = (short)mv; cpb[j] = (short)0x3F80; }
    f32x4 zf = (f32x4){0.f, 0.f, 0.f, 0.f};
    f32x4 rowp = __builtin_amdgcn_mfma_f32_16x16x32_bf16(cpa, cpb, zf, 0, 0, 0);
    f32x4 colp = __builtin_amdgcn_mfma_f32_16x16x32_bf16(cpb, cpa, zf, 0, 0, 0);
    int rowm[4], colm[4];
    #pragma unroll
    for (int r = 0; r < 4; r++) {
        rowm[r] = (((int)(rowp[r] * 0.03125f + 0.5f)) - 1) & 15;
        colm[r] = (((int)(colp[r] * 0.03125f + 0.5f)) - 1) & 15;
    }

    if (t < TOPK) idxs[t] = IDX[(size_t)g*TOPK + t];
    // Q: bf16-split with zero padding (rows 8..15, cols 48..71)
    for (int i = t; i < 16*72; i += 512) {
        int r = i / 72, c = i % 72;
        unsigned short h = 0, l = 0;
        if (r < 8 && c < 48) bsplit(Y[(size_t)g*QKV_COLS + C_Q + r*48 + c], h, l);
        Qh[r][c] = h; Ql[r][c] = l;
    }
    __syncthreads();

    // gather: 128 rows x 24 slots (18 data uint4 + 6 zero uint4)
    #pragma unroll
    for (int i = 0; i < 6; i++) {
        int e = t + 512*i;
        int row = e / 24, s = e % 24;
        size_t ridx = (size_t)(b*NSEQ + idxs[row]) * 96;
        uint4 z = {0, 0, 0, 0};
        if (s < 6)       *(uint4*)&Kh[row][s*8]        = ((const uint4*)(KVh + ridx))[s];
        else if (s < 12) *(uint4*)&Vh[row][(s-6)*8]    = ((const uint4*)(KVh + ridx))[s];
        else if (s < 18) *(uint4*)&Kl[row][(s-12)*8]   = ((const uint4*)(KVl + ridx))[s-12];
        else if (s < 21) *(uint4*)&Kh[row][48+(s-18)*8] = z;
        else             *(uint4*)&Kl[row][48+(s-21)*8] = z;
    }
    __syncthreads();

    // ---- QK: wave wid owns keys wid*16..wid*16+15 ----
    {
        f32x4 acc = zf;
        #pragma unroll
        for (int k0 = 0; k0 < 64; k0 += 32) {
            s16x8 qh = *(const s16x8*)&Qh[ml][k0 + kq*8];
            s16x8 ql = *(const s16x8*)&Ql[ml][k0 + kq*8];
            s16x8 kh = *(const s16x8*)&Kh[wid*16 + ml][k0 + kq*8];
            s16x8 kl = *(const s16x8*)&Kl[wid*16 + ml][k0 + kq*8];
            acc = __builtin_amdgcn_mfma_f32_16x16x32_bf16(qh, kh, acc, 0, 0, 0);
            acc = __builtin_amdgcn_mfma_f32_16x16x32_bf16(qh, kl, acc, 0, 0, 0);
            acc = __builtin_amdgcn_mfma_f32_16x16x32_bf16(ql, kh, acc, 0, 0, 0);
        }
        #pragma unroll
        for (int r = 0; r < 4; r++)
            Ssc[rowm[r]][wid*16 + colm[r]] = acc[r];
    }
    __syncthreads();

    // ---- softmax (heads 0..7), probs -> bf16-hi Ph; zero pad rows ----
    if (t < 256) {
        const int h = t >> 5, j0 = t & 31;
        float lo[4];
        #pragma unroll
        for (int i = 0; i < 4; i++) lo[i] = Ssc[h][j0 + 32*i] * ATT_SCALE;
        float m = fmaxf(fmaxf(lo[0], lo[1]), fmaxf(lo[2], lo[3]));
        for (int d = 16; d >= 1; d >>= 1) m = fmaxf(m, __shfl_xor(m, d, 64));
        float e0[4], sum = 0.f;
        #pragma unroll
        for (int i = 0; i < 4; i++) { e0[i] = __expf(lo[i] - m); sum += e0[i]; }
        for (int d = 16; d >= 1; d >>= 1) sum += __shfl_xor(sum, d, 64);
        float inv = 1.0f / sum;
        #pragma unroll
        for (int i = 0; i < 4; i++) Ph[h][j0 + 32*i] = b16hi(e0[i] * inv);
        #pragma unroll
        for (int i2 = 0; i2 < 4; i2++) {
            int e = t + 256*i2;
            Ph[8 + (e >> 7)][e & 127] = 0;
        }
    }
    __syncthreads();

    // ---- PV: waves 0..2 own dd tiles 0..15 / 16..31 / 32..47 ----
    if (wid < 3) {
        f32x4 pacc = zf;
        #pragma unroll
        for (int ks = 0; ks < 4; ks++) {
            s16x8 pf = *(const s16x8*)&Ph[ml][ks*32 + kq*8];
            s16x8 vf;
            #pragma unroll
            for (int e = 0; e < 8; e++)
                vf[e] = (short)Vh[ks*32 + kq*8 + e][wid*16 + ml];
            pacc = __builtin_amdgcn_mfma_f32_16x16x32_bf16(pf, vf, pacc, 0, 0, 0);
        }
        #pragma unroll
        for (int r = 0; r < 4; r++) {
            int hh = rowm[r];
            if (hh < 8) {
                int dd = wid*16 + colm[r];
                unsigned short ch, cl;
                bsplit(pacc[r], ch, cl);
                ctx_hi[(size_t)g*(NH*DV) + hh*DV + dd] = ch;
                ctx_lo[(size_t)g*(NH*DV) + hh*DV + dd] = cl;
            }
        }
    }
}

// ------------------------------------------------------------------
extern "C" void kernel_launch(void* const* d_in, const int* in_sizes, int n_in,
                              void* d_out, int out_size, void* d_ws, size_t ws_size,
                              hipStream_t stream) {
    const float* x      = (const float*)d_in[0];
    const float* wq_idx = (const float*)d_in[1];
    const float* wk_idx = (const float*)d_in[2];
    const float* ww_idx = (const float*)d_in[3];
    const float* wq     = (const float*)d_in[4];
    const float* wk     = (const float*)d_in[5];
    const float* wv     = (const float*)d_in[6];
    const float* wo     = (const float*)d_in[7];
    float* out = (float*)d_out;
    char*  ws  = (char*)d_ws;

    size_t off = 0;
    auto carve = [&](size_t bytes) { size_t o = off; off = (off + bytes + 255) & ~(size_t)255; return o; };
    size_t oWqh = carve((size_t)QKV_COLS*DMODEL*2);
    size_t oWql = carve((size_t)QKV_COLS*DMODEL*2);
    size_t oWoh = carve((size_t)DMODEL*DMODEL*2);
    size_t oWol = carve((size_t)DMODEL*DMODEL*2);
    size_t oWi  = carve((size_t)DMODEL*IDX_COLS*4);
    size_t oXh  = carve((size_t)NQ*DMODEL*2);
    size_t oXl  = carve((size_t)NQ*DMODEL*2);
    size_t oY   = carve((size_t)NQ*QKV_COLS*4);
    size_t oP   = carve((size_t)NQ*IDX_COLS*8);
    size_t oIdx = carve((size_t)NQ*TOPK*4);
    size_t oCh  = carve((size_t)NQ*NH*DV*2);
    size_t oCl  = carve((size_t)NQ*NH*DV*2);
    size_t oKVh = carve((size_t)NQ*96*2);
    size_t oKVl = carve((size_t)NQ*96*2);
    size_t oKL  = off;

    // chunk region: one sortable u32 key per score
    int QC = NQ;
    while (QC > 32 && oKL + (size_t)QC*NSEQ*4 > ws_size) QC >>= 1;

    unsigned short* WqT_hi = (unsigned short*)(ws + oWqh);
    unsigned short* WqT_lo = (unsigned short*)(ws + oWql);
    unsigned short* WoT_hi = (unsigned short*)(ws + oWoh);
    unsigned short* WoT_lo = (unsigned short*)(ws + oWol);
    float*  Wi_cat = (float*)(ws + oWi);
    unsigned short* xhi = (unsigned short*)(ws + oXh);
    unsigned short* xlo = (unsigned short*)(ws + oXl);
    float*  Y      = (float*)(ws + oY);
    double* P      = (double*)(ws + oP);
    int*    IDX    = (int*)(ws + oIdx);
    unsigned short* ctx_hi = (unsigned short*)(ws + oCh);
    unsigned short* ctx_lo = (unsigned short*)(ws + oCl);
    unsigned short* KVh = (unsigned short*)(ws + oKVh);
    unsigned short* KVl = (unsigned short*)(ws + oKVl);
    unsigned int* K32 = (unsigned int*)(ws + oKL);

    int ncat = QKV_COLS*DMODEL + DMODEL*DMODEL + DMODEL*IDX_COLS;
    k_split<<<(NQ*DMODEL + 255)/256, 256, 0, stream>>>(x, xhi, xlo);
    k_concat<<<(ncat + 255)/256, 256, 0, stream>>>(wq_idx, wk_idx, ww_idx, wq, wk, wv, wo,
                                                   WqT_hi, WqT_lo, WoT_hi, WoT_lo, Wi_cat);
    k_gemm_mfma<<<dim3((QKV_COLS + 63)/64, NQ/128), 256, 0, stream>>>(xhi, xlo, WqT_hi, WqT_lo, Y, QKV_COLS, QKV_COLS);
    k_kvsplit<<<(NQ*96 + 255)/256, 256, 0, stream>>>(Y, KVh, KVl);
    k_proj64<<<NQ/32, 256, 0, stream>>>(x, Wi_cat, P);
    for (int qs = 0; qs < NQ; qs += QC) {
        k_score_mfma<<<dim3(NSEQ/128, QC/32), 256, 0, stream>>>(P, K32, qs);
        k_topk<<<QC, 256, 0, stream>>>(K32, IDX, qs);
    }
    k_attn<<<NQ, 512, 0, stream>>>(Y, KVh, KVl, IDX, ctx_hi, ctx_lo);
    k_gemm_mfma<<<dim3(DMODEL/64, NQ/128), 256, 0, stream>>>(ctx_hi, ctx_lo, WoT_hi, WoT_lo, out, DMODEL, DMODEL);
}

// Round 13
// 443.072 us; speedup vs baseline: 1.0970x; 1.0970x over previous
//
#include <hip/hip_runtime.h>
#include <math.h>

// ---- problem dims ----
#define NB 2
#define NSEQ 4096
#define DMODEL 384
#define NH 8
#define DKQ 48
#define DV 48
#define TOPK 128
#define NQ (NB*NSEQ)          // 8192 total query rows

// fp32 combined projection: [q(384) | k(48) | v(48)] = 480 cols
#define QKV_COLS 480
#define C_Q 0
#define C_K 384
#define C_V 432
// fp64 indexer projection Pd[8192][128]: [qi0(32)|qi1(32)|ki(32)|w(2)|pad]
#define IDX_COLS 128
#define P_QI 0
#define P_KI 64
#define P_W  96
#define ATT_SCALE 0.14433756729740643f   // 48^-0.5

typedef double v4d  __attribute__((ext_vector_type(4)));
typedef float  f32x4 __attribute__((ext_vector_type(4)));
typedef short  s16x8 __attribute__((ext_vector_type(8)));

// round-to-nearest-even bf16 split: v ~= hi + lo
__device__ inline void bsplit(float v, unsigned short& h, unsigned short& l) {
    unsigned hb = __float_as_uint(v);
    unsigned short hi = (unsigned short)((hb + 0x7FFFu + ((hb >> 16) & 1u)) >> 16);
    float hf = __uint_as_float(((unsigned)hi) << 16);
    float r = v - hf;
    unsigned rb = __float_as_uint(r);
    unsigned short lo = (unsigned short)((rb + 0x7FFFu + ((rb >> 16) & 1u)) >> 16);
    h = hi; l = lo;
}

// ------------------------------------------------------------------
// split x into bf16 hi/lo
// ------------------------------------------------------------------
__global__ void k_split(const float* __restrict__ x,
                        unsigned short* __restrict__ xhi, unsigned short* __restrict__ xlo) {
    int i = blockIdx.x * 256 + threadIdx.x;
    if (i < NQ * DMODEL) {
        unsigned short h, l;
        bsplit(x[i], h, l);
        xhi[i] = h; xlo[i] = l;
    }
}

// ------------------------------------------------------------------
// concat + transpose + split weights
// ------------------------------------------------------------------
__global__ void k_concat(const float* __restrict__ wq_idx, const float* __restrict__ wk_idx,
                         const float* __restrict__ ww_idx, const float* __restrict__ wq,
                         const float* __restrict__ wk, const float* __restrict__ wv,
                         const float* __restrict__ wo,
                         unsigned short* __restrict__ WqT_hi, unsigned short* __restrict__ WqT_lo,
                         unsigned short* __restrict__ WoT_hi, unsigned short* __restrict__ WoT_lo,
                         float* __restrict__ Wi_cat) {
    int i = blockIdx.x * 256 + threadIdx.x;
    const int NQK = QKV_COLS * DMODEL;          // 184320
    const int NWO = DMODEL * DMODEL;            // 147456
    if (i < NQK) {
        int n = i / DMODEL, k = i % DMODEL;
        float v;
        if (n < 384)      v = wq[(size_t)k*384 + n];
        else if (n < 432) v = wk[(size_t)k*48 + (n-384)];
        else              v = wv[(size_t)k*48 + (n-432)];
        unsigned short h, l; bsplit(v, h, l);
        WqT_hi[i] = h; WqT_lo[i] = l;
    } else if (i < NQK + NWO) {
        int j = i - NQK;
        int n = j / DMODEL, k = j % DMODEL;
        float v = wo[(size_t)k*384 + n];
        unsigned short h, l; bsplit(v, h, l);
        WoT_hi[j] = h; WoT_lo[j] = l;
    } else if (i < NQK + NWO + DMODEL*IDX_COLS) {
        int j = i - NQK - NWO;
        int d = j / IDX_COLS, c = j % IDX_COLS;
        float v;
        if (c < 64)       v = wq_idx[d*64 + c];
        else if (c < 96)  v = wk_idx[d*32 + (c-64)];
        else if (c < 98)  v = ww_idx[d*2 + (c-96)];
        else              v = 0.f;
        Wi_cat[j] = v;
    }
}

// ------------------------------------------------------------------
// split-bf16 MFMA GEMM: C[M x N] = (Ahi+Alo)[M x 384] @ (Bhi+Blo)^T
// ------------------------------------------------------------------
#define GLDK 40   // shorts per LDS row (32 + 8 pad)
__global__ __launch_bounds__(256) void k_gemm_mfma(
        const unsigned short* __restrict__ Ahi, const unsigned short* __restrict__ Alo,
        const unsigned short* __restrict__ Bhi, const unsigned short* __restrict__ Blo,
        float* __restrict__ C, int N, int ldc) {
    __shared__ unsigned short At[2][128][GLDK];
    __shared__ unsigned short Bt[2][64][GLDK];
    const int t = threadIdx.x;
    const int lane = t & 63, wid = t >> 6;
    const int row0 = blockIdx.y * 128, col0 = blockIdx.x * 64;
    const int ml = lane & 15, kq = lane >> 4;
    const int wm = (wid & 1) * 64, wn = (wid >> 1) * 32;

    // ---- layout calibration probes ----
    unsigned short mv = (unsigned short)(__float_as_uint((float)(ml + 1)) >> 16);
    unsigned short one = 0x3F80;
    s16x8 pa, pb;
    #pragma unroll
    for (int j = 0; j < 8; j++) { pa[j] = (short)mv; pb[j] = (short)one; }
    f32x4 zf = (f32x4){0.f, 0.f, 0.f, 0.f};
    f32x4 rowp = __builtin_amdgcn_mfma_f32_16x16x32_bf16(pa, pb, zf, 0, 0, 0);
    f32x4 colp = __builtin_amdgcn_mfma_f32_16x16x32_bf16(pb, pa, zf, 0, 0, 0);
    int rowm[4], colm[4];
    #pragma unroll
    for (int r = 0; r < 4; r++) {
        rowm[r] = (((int)(rowp[r] * 0.03125f + 0.5f)) - 1) & 15;
        colm[r] = (((int)(colp[r] * 0.03125f + 0.5f)) - 1) & 15;
    }

    f32x4 acc[4][2];
    #pragma unroll
    for (int mt = 0; mt < 4; mt++)
        #pragma unroll
        for (int nt = 0; nt < 2; nt++) acc[mt][nt] = zf;

    for (int k0 = 0; k0 < DMODEL; k0 += 32) {
        #pragma unroll
        for (int i = 0; i < 4; i++) {
            int ch = t + 256*i;
            int arr = ch >> 9, rem = ch & 511;
            int r = rem >> 2, p = rem & 3;
            const unsigned short* src = arr ? Alo : Ahi;
            *(int4*)&At[arr][r][p*8] = *(const int4*)(src + (size_t)(row0 + r)*DMODEL + k0 + p*8);
        }
        #pragma unroll
        for (int i = 0; i < 2; i++) {
            int ch = t + 256*i;
            int arr = ch >> 8, rem = ch & 255;
            int r = rem >> 2, p = rem & 3;
            const unsigned short* src = arr ? Blo : Bhi;
            int gc = col0 + r;
            int4 v = {0, 0, 0, 0};
            if (gc < N) v = *(const int4*)(src + (size_t)gc*DMODEL + k0 + p*8);
            *(int4*)&Bt[arr][r][p*8] = v;
        }
        __syncthreads();
        s16x8 af[4][2], bfr[2][2];
        #pragma unroll
        for (int mt = 0; mt < 4; mt++)
            #pragma unroll
            for (int h = 0; h < 2; h++)
                af[mt][h] = *(const s16x8*)&At[h][wm + mt*16 + ml][kq*8];
        #pragma unroll
        for (int nt = 0; nt < 2; nt++)
            #pragma unroll
            for (int h = 0; h < 2; h++)
                bfr[nt][h] = *(const s16x8*)&Bt[h][wn + nt*16 + ml][kq*8];
        #pragma unroll
        for (int mt = 0; mt < 4; mt++)
            #pragma unroll
            for (int nt = 0; nt < 2; nt++) {
                acc[mt][nt] = __builtin_amdgcn_mfma_f32_16x16x32_bf16(af[mt][0], bfr[nt][0], acc[mt][nt], 0, 0, 0);
                acc[mt][nt] = __builtin_amdgcn_mfma_f32_16x16x32_bf16(af[mt][0], bfr[nt][1], acc[mt][nt], 0, 0, 0);
                acc[mt][nt] = __builtin_amdgcn_mfma_f32_16x16x32_bf16(af[mt][1], bfr[nt][0], acc[mt][nt], 0, 0, 0);
            }
        __syncthreads();
    }
    #pragma unroll
    for (int mt = 0; mt < 4; mt++)
        #pragma unroll
        for (int nt = 0; nt < 2; nt++)
            #pragma unroll
            for (int r = 0; r < 4; r++) {
                int rr = row0 + wm + mt*16 + rowm[r];
                int cc = col0 + wn + nt*16 + colm[r];
                if (cc < N) C[(size_t)rr*ldc + cc] = acc[mt][nt][r];
            }
}

// ------------------------------------------------------------------
// fp64-accumulated indexer projection: Pd[8192][128] = x @ Wi_cat
// ------------------------------------------------------------------
__global__ __launch_bounds__(256) void k_proj64(const float* __restrict__ A,
                                                const float* __restrict__ W,
                                                double* __restrict__ P) {
    __shared__ float At[16][32];
    __shared__ float Bt[16][IDX_COLS];
    const int t  = threadIdx.x;
    const int tx = t & 15;
    const int ty = t >> 4;
    const int row0 = blockIdx.x * 32;
    double acc[2][8] = {};

    for (int k0 = 0; k0 < DMODEL; k0 += 16) {
        if (t < 128) {
            int m = t >> 2, kc = t & 3;
            float4 a = *(const float4*)(A + (size_t)(row0 + m)*DMODEL + k0 + kc*4);
            At[kc*4+0][m] = a.x; At[kc*4+1][m] = a.y;
            At[kc*4+2][m] = a.z; At[kc*4+3][m] = a.w;
        }
        for (int i = 0; i < 2; i++) {
            int lin = t + i*256;
            int kk = lin >> 5, c4 = lin & 31;
            float4 b = *(const float4*)(W + (size_t)(k0+kk)*IDX_COLS + c4*4);
            *(float4*)&Bt[kk][c4*4] = b;
        }
        __syncthreads();
        for (int kk = 0; kk < 16; kk++) {
            float a2[2], b8[8];
            a2[0] = At[kk][ty*2]; a2[1] = At[kk][ty*2+1];
            *(float4*)&b8[0] = *(const float4*)&Bt[kk][tx*8];
            *(float4*)&b8[4] = *(const float4*)&Bt[kk][tx*8+4];
            for (int i = 0; i < 2; i++)
                for (int j = 0; j < 8; j++)
                    acc[i][j] += (double)a2[i] * (double)b8[j];
        }
        __syncthreads();
    }
    for (int i = 0; i < 2; i++)
        for (int j = 0; j < 8; j++)
            P[(size_t)(row0 + ty*2 + i)*IDX_COLS + tx*8 + j] = acc[i][j];
}

// ------------------------------------------------------------------
// fp64 index scores via MFMA f64 16x16x4, self-calibrated C/D layout.
// Emits ONE f32-rounded sortable-u32 key per score. Plain store:
// K32 (134 MB) stays L3-resident for k_topk's reads.
// ------------------------------------------------------------------
__global__ __launch_bounds__(256) void k_score_mfma(const double* __restrict__ P,
                                                    unsigned int* __restrict__ K32,
                                                    int qstart) {
    __shared__ double A0[32][33];
    __shared__ double A1[32][33];
    __shared__ double Bk[32][129];
    __shared__ double wsh[2][32];
    const int t = threadIdx.x;
    const int lane = t & 63;
    const int wid = t >> 6;
    const int g0 = qstart + blockIdx.y * 32;
    const int b  = g0 / NSEQ;
    const int s0 = blockIdx.x * 128;

    for (int i = 0; i < 8; i++) {
        int lin = t + i*256;
        int q = lin >> 6, c = lin & 63;
        double v = P[(size_t)(g0 + q)*IDX_COLS + P_QI + c];
        if (c < 32) A0[c][q] = v; else A1[c-32][q] = v;
    }
    for (int i = 0; i < 16; i++) {
        int lin = t + i*256;
        int s = lin >> 5, c = lin & 31;
        Bk[c][s] = P[(size_t)(b*NSEQ + s0 + s)*IDX_COLS + P_KI + c];
    }
    if (t < 64) wsh[t & 1][t >> 1] = P[(size_t)(g0 + (t >> 1))*IDX_COLS + P_W + (t & 1)];

    const int qw = (wid & 1) * 16;
    const int sw = (wid >> 1) * 64;
    const int ml = lane & 15;
    const int kl = lane >> 4;

    v4d zero = (v4d){0.0, 0.0, 0.0, 0.0};
    v4d rowp = __builtin_amdgcn_mfma_f64_16x16x4f64((double)(ml+1), 1.0, zero, 0, 0, 0);
    v4d colp = __builtin_amdgcn_mfma_f64_16x16x4f64(1.0, (double)(ml+1), zero, 0, 0, 0);
    int rowm[4], colm[4];
    #pragma unroll
    for (int r = 0; r < 4; r++) {
        rowm[r] = (((int)(rowp[r] * 0.25 + 0.5)) - 1) & 15;
        colm[r] = (((int)(colp[r] * 0.25 + 0.5)) - 1) & 15;
    }

    __syncthreads();

    v4d acc0[4], acc1[4];
    #pragma unroll
    for (int st = 0; st < 4; st++) { acc0[st] = zero; acc1[st] = zero; }

    #pragma unroll
    for (int k4 = 0; k4 < 8; k4++) {
        int k = k4*4 + kl;
        double a0 = A0[k][qw + ml];
        double a1 = A1[k][qw + ml];
        #pragma unroll
        for (int st = 0; st < 4; st++) {
            double bb = Bk[k][sw + st*16 + ml];
            acc0[st] = __builtin_amdgcn_mfma_f64_16x16x4f64(a0, bb, acc0[st], 0, 0, 0);
            acc1[st] = __builtin_amdgcn_mfma_f64_16x16x4f64(a1, bb, acc1[st], 0, 0, 0);
        }
    }

    #pragma unroll
    for (int reg = 0; reg < 4; reg++) {
        int q = qw + rowm[reg];
        double w0 = wsh[0][q], w1 = wsh[1][q];
        #pragma unroll
        for (int st = 0; st < 4; st++) {
            double sc = w0 * fmax(acc0[st][reg], 0.0) + w1 * fmax(acc1[st][reg], 0.0);
            size_t oidx = (size_t)(blockIdx.y*32 + q)*NSEQ + s0 + sw + st*16 + colm[reg];
            float sf = (float)sc;
            unsigned int ub = __float_as_uint(sf);
            unsigned int u = (ub & 0x80000000u) ? ~ub : (ub | 0x80000000u);
            K32[oidx] = u;
        }
    }
}

// ------------------------------------------------------------------
// Block-per-query top-128: u32 f32-sortable keys, single-stage.
// (unchanged - proven)
// ------------------------------------------------------------------
__global__ __launch_bounds__(256) void k_topk(const unsigned int* __restrict__ K32,
                                              int* __restrict__ IDX, int qstart) {
    __shared__ unsigned int pool[1024];   // fast: CK[512]|CI[512]; fallback: hist[4][256]
    __shared__ unsigned int wred[4];
    __shared__ unsigned int s_b, s_need, s_flag, s_cnt, s_n;
    unsigned int* CK = pool;
    int* CI = (int*)(pool + 512);
    const int t = threadIdx.x, lane = t & 63;
    const int wid = t >> 6;
    const int q = blockIdx.x;
    const unsigned int* krow = K32 + (size_t)q * NSEQ;
    int* orow = IDX + (size_t)(qstart + q) * TOPK;

    // slot j (0..15) <-> index i = (j>>2)*1024 + t*4 + (j&3)
    unsigned int kr[16];
    #pragma unroll
    for (int jj = 0; jj < 4; jj++) {
        uint4 v = *(const uint4*)(krow + (t*4 + 1024*jj));
        kr[jj*4+0] = v.x; kr[jj*4+1] = v.y; kr[jj*4+2] = v.z; kr[jj*4+3] = v.w;
    }
    unsigned int mymax = kr[0];
    #pragma unroll
    for (int j = 1; j < 16; j++) mymax = kr[j] > mymax ? kr[j] : mymax;
    const unsigned int p16 = mymax >> 16;

    // per-wave bisection: largest Tw with >=32 lane-maxima prefix16 >= Tw
    unsigned int Tw = 0;
    #pragma unroll
    for (int bit = 15; bit >= 0; --bit) {
        unsigned int trial = Tw | (1u << bit);
        if (__popcll(__ballot(p16 >= trial)) >= 32) Tw = trial;
    }
    if (lane == 0) wred[wid] = Tw;
    if (t == 0) { s_cnt = 0; s_n = 0; s_need = TOPK; s_flag = 0; }
    __syncthreads();
    unsigned int T16 = wred[0];
    T16 = wred[1] < T16 ? wred[1] : T16;
    T16 = wred[2] < T16 ? wred[2] : T16;
    T16 = wred[3] < T16 ? wred[3] : T16;

    // compact candidates (prefix16 >= T16), bounded at 512
    #pragma unroll
    for (int j = 0; j < 16; j++) {
        if ((kr[j] >> 16) >= T16) {
            unsigned int pos = atomicAdd(&s_n, 1u);
            if (pos < 512u) { CK[pos] = kr[j]; CI[pos] = (j >> 2)*1024 + t*4 + (j & 3); }
        }
    }
    __syncthreads();
    const unsigned int n = s_n;

    if (n <= 512u) {
        // ---------- FAST PATH: wave 0 exact bisection select ----------
        if (wid == 0) {
            unsigned int ck[8]; int ci[8]; bool cv[8];
            #pragma unroll
            for (int e = 0; e < 8; e++) {
                int id = lane + e*64;
                cv[e] = (unsigned int)id < n;
                ck[e] = cv[e] ? CK[id] : 0u;
                ci[e] = cv[e] ? CI[id] : 0;
            }
            // exact 128th-largest key: largest T with cnt(>=T) >= TOPK
            unsigned int T = 0;
            for (int bit = 31; bit >= 0; --bit) {
                unsigned int trial = T | (1u << bit);
                unsigned int c = 0;
                #pragma unroll
                for (int e = 0; e < 8; e++)
                    c += (unsigned int)__popcll(__ballot(cv[e] && ck[e] >= trial));
                if (c >= (unsigned int)TOPK) T = trial;
            }
            unsigned int G = 0, E = 0;
            #pragma unroll
            for (int e = 0; e < 8; e++) {
                G += (unsigned int)__popcll(__ballot(cv[e] && ck[e] > T));
                E += (unsigned int)__popcll(__ballot(cv[e] && ck[e] == T));
            }
            const unsigned int need = (unsigned int)TOPK - G;
            const unsigned long long ltm = (1ull << lane) - 1ull;

            unsigned int cbase = 0;
            #pragma unroll
            for (int e = 0; e < 8; e++) {              // emit strict-greater
                bool em = cv[e] && ck[e] > T;
                unsigned long long m = __ballot(em);
                if (em) orow[cbase + __popcll(m & ltm)] = ci[e];
                cbase += (unsigned int)__popcll(m);
            }
            if (E == need) {                            // ties exactly fill
                #pragma unroll
                for (int e = 0; e < 8; e++) {
                    bool em = cv[e] && ck[e] == T;
                    unsigned long long m = __ballot(em);
                    if (em) orow[cbase + __popcll(m & ltm)] = ci[e];
                    cbase += (unsigned int)__popcll(m);
                }
            } else {
                // need smallest indices among ==T: max r with cntLE(r) <= need
                unsigned int r = 0;
                for (int bit = 11; bit >= 0; --bit) {
                    unsigned int trial = r | (1u << bit);
                    unsigned int c = 0;
                    #pragma unroll
                    for (int e = 0; e < 8; e++)
                        c += (unsigned int)__popcll(__ballot(cv[e] && ck[e] == T &&
                                 (unsigned int)ci[e] <= trial));
                    if (c <= need) r = trial;
                }
                #pragma unroll
                for (int e = 0; e < 8; e++) {
                    bool em = cv[e] && ck[e] == T && (unsigned int)ci[e] <= r;
                    unsigned long long m = __ballot(em);
                    if (em) orow[cbase + __popcll(m & ltm)] = ci[e];
                    cbase += (unsigned int)__popcll(m);
                }
            }
        }
        return;
    }

    // ---------- FALLBACK (degenerate rows): radix-byte select ----------
    unsigned int amask = 0;
    #pragma unroll
    for (int j = 0; j < 16; j++)
        if ((kr[j] >> 16) >= T16) amask |= (1u << j);

    unsigned int (*hist)[256] = (unsigned int (*)[256])pool;
    auto clearhist = [&]() {
        #pragma unroll
        for (int w = 0; w < 4; w++) hist[w][t] = 0;
        __syncthreads();
    };
    auto decide = [&]() {
        if (wid == 0) {
            unsigned int c[4];
            #pragma unroll
            for (int k2 = 0; k2 < 4; k2++)
                c[k2] = hist[0][lane*4+k2] + hist[1][lane*4+k2]
                      + hist[2][lane*4+k2] + hist[3][lane*4+k2];
            unsigned int run = c[0] + c[1] + c[2] + c[3];
            #pragma unroll
            for (int d2 = 1; d2 < 64; d2 <<= 1) {
                unsigned int v = __shfl_down(run, d2, 64);
                if (lane + d2 < 64) run += v;
            }
            unsigned int need = s_need;
            unsigned int Sb[5];
            Sb[0] = run; Sb[1] = run - c[0]; Sb[2] = Sb[1] - c[1];
            Sb[3] = Sb[2] - c[2]; Sb[4] = Sb[3] - c[3];
            #pragma unroll
            for (int j = 0; j < 4; j++) {
                if (Sb[j] >= need && Sb[j+1] < need) {
                    s_b = (unsigned int)(lane*4 + j);
                    s_need = need - Sb[j+1];
                    s_flag = (need - Sb[j+1] == c[j]) ? 1u : 0u;
                }
            }
        }
        __syncthreads();
    };

    #pragma unroll 1
    for (int level = 0; level < 4; ++level) {
        const int sh = 24 - 8*level;
        clearhist();
        #pragma unroll
        for (int j = 0; j < 16; j++) {
            if ((amask >> j) & 1u)
                atomicAdd(&hist[wid][(kr[j] >> sh) & 255u], 1u);
        }
        __syncthreads();
        decide();
        const unsigned int bstar = s_b;

        if (s_flag) {
            #pragma unroll
            for (int j = 0; j < 16; j++) {
                if (((amask >> j) & 1u) && (((kr[j] >> sh) & 255u) >= bstar))
                    orow[atomicAdd(&s_cnt, 1u)] = (j >> 2)*1024 + t*4 + (j & 3);
            }
            return;
        }
        unsigned int nm = 0;
        #pragma unroll
        for (int j = 0; j < 16; j++) {
            if ((amask >> j) & 1u) {
                unsigned int d = (kr[j] >> sh) & 255u;
                if (d > bstar) orow[atomicAdd(&s_cnt, 1u)] = (j >> 2)*1024 + t*4 + (j & 3);
                else if (d == bstar) nm |= (1u << j);
            }
        }
        amask = nm;
    }

    // full 32-bit ties: lowest indices fill the remaining slots
    const unsigned int needF = s_need;
    unsigned int base = 0;
    #pragma unroll 1
    for (int jj = 0; jj < 4; jj++) {
        unsigned int m4 = (amask >> (jj*4)) & 0xFu;
        unsigned int cnt = __popc(m4);
        unsigned int inc = cnt;
        #pragma unroll
        for (int d2 = 1; d2 < 64; d2 <<= 1) {
            unsigned int v = __shfl_up(inc, d2, 64);
            if (lane >= d2) inc += v;
        }
        if (lane == 63) wred[wid] = inc;
        __syncthreads();
        unsigned int woff = 0;
        for (int w2 = 0; w2 < wid; w2++) woff += wred[w2];
        unsigned int T = wred[0] + wred[1] + wred[2] + wred[3];
        unsigned int p = base + woff + inc - cnt;
        #pragma unroll
        for (int c = 0; c < 4; c++) {
            if ((m4 >> c) & 1u) {
                if (p < needF) orow[atomicAdd(&s_cnt, 1u)] = jj*1024 + t*4 + c;
                p++;
            }
        }
        base += T;
        __syncthreads();
    }
}

// ------------------------------------------------------------------
// Fused attention v5: v11 math (identical numerics), K/V time-share
// one 32 KB LDS buffer. V rides in registers through QK+softmax, then
// scatters into the dead K buffer. LDS 62->38.3 KB => 3 blocks/CU.
// ------------------------------------------------------------------
__global__ __launch_bounds__(512, 6) void k_attn(const float* __restrict__ Y,
                                                 const int* __restrict__ IDX,
                                                 unsigned short* __restrict__ ctx_hi,
                                                 unsigned short* __restrict__ ctx_lo) {
    __shared__ float smem[TOPK * 64];   // 32 KB: K swizzled during QK, then V^T
    __shared__ float qsh[NH*DKQ];       // 1.5 KB
    __shared__ float prs[NH*TOPK];      // 4 KB
    __shared__ int   idxs[TOPK];        // 0.5 KB
    const int g = blockIdx.x;
    const int b = g / NSEQ;
    const int t = threadIdx.x;
    const int lane = t & 63, wid = t >> 6;

    if (t < TOPK) idxs[t] = IDX[(size_t)g*TOPK + t];
    if (t < NH*DKQ) qsh[t] = Y[(size_t)g*QKV_COLS + C_Q + t];
    __syncthreads();

    // gather: K -> LDS (swizzled), V -> registers (3 float4/thread)
    // slot e = t + 512*i : row j = e/12, col-quad p = e%12
    float4 vreg[3];
    #pragma unroll
    for (int i = 0; i < 3; i++) {
        int e = t + 512*i;
        int j = e / 12, p = e % 12;
        const float* src = Y + (size_t)(b*NSEQ + idxs[j])*QKV_COLS;
        *(float4*)&smem[j*64 + ((p ^ (j & 7)) * 4)] = *(const float4*)(src + C_K + p*4);
        vreg[i] = *(const float4*)(src + C_V + p*4);
    }
    __syncthreads();

    // ---- QK + softmax: wave wid = head wid; lane handles rows lane, lane+64 ----
    float4 qf[12];
    #pragma unroll
    for (int c = 0; c < 12; c++) qf[c] = *(const float4*)&qsh[wid*DKQ + c*4];
    float lo0 = 0.f, lo1 = 0.f;
    const int sw = (lane & 7);
    #pragma unroll
    for (int c = 0; c < 12; c++) {
        // physical col (c^sw) of row `lane` holds LOGICAL K column c
        float4 k0 = *(const float4*)&smem[lane*64 + (c ^ sw) * 4];
        float4 k1 = *(const float4*)&smem[(lane + 64)*64 + (c ^ ((lane + 64) & 7)) * 4];
        float4 qv = qf[c];
        lo0 += qv.x*k0.x + qv.y*k0.y + qv.z*k0.z + qv.w*k0.w;
        lo1 += qv.x*k1.x + qv.y*k1.y + qv.z*k1.z + qv.w*k1.w;
    }
    lo0 *= ATT_SCALE; lo1 *= ATT_SCALE;
    float m = fmaxf(lo0, lo1);
    #pragma unroll
    for (int d = 32; d >= 1; d >>= 1) m = fmaxf(m, __shfl_xor(m, d, 64));
    float e0 = __expf(lo0 - m), e1 = __expf(lo1 - m);
    float sum = e0 + e1;
    #pragma unroll
    for (int d = 32; d >= 1; d >>= 1) sum += __shfl_xor(sum, d, 64);
    float inv = 1.0f / sum;
    prs[wid*TOPK + lane]      = e0 * inv;
    prs[wid*TOPK + lane + 64] = e1 * inv;
    __syncthreads();   // all QK reads of smem done; prs visible

    // ---- scatter V regs into smem as V^T (v11 layout) ----
    #pragma unroll
    for (int i = 0; i < 3; i++) {
        int e = t + 512*i;
        int j = e / 12, p = e % 12;
        #pragma unroll
        for (int c = 0; c < 4; c++) {
            int dd = p*4 + c;
            smem[dd*TOPK + (((j >> 2) ^ (dd & 31)) << 2) + (j & 3)] = ((const float*)&vreg[i])[c];
        }
    }
    __syncthreads();

    // ---- PV: wave wid = head wid; lanes 0..47 = dd ----
    if (lane < DV) {
        const int dd = lane;
        const int dsw = dd & 31;
        float acc = 0.f;
        #pragma unroll
        for (int jb = 0; jb < 32; jb++) {
            float4 pv = *(const float4*)&prs[wid*TOPK + jb*4];             // wave-uniform
            float4 vt = *(const float4*)&smem[dd*TOPK + ((jb ^ dsw) << 2)]; // V[jb*4+i][dd]
            acc += pv.x*vt.x + pv.y*vt.y + pv.z*vt.z + pv.w*vt.w;
        }
        unsigned short ch, cl;
        bsplit(acc, ch, cl);
        ctx_hi[(size_t)g*(NH*DV) + wid*DV + dd] = ch;
        ctx_lo[(size_t)g*(NH*DV) + wid*DV + dd] = cl;
    }
}

// ------------------------------------------------------------------
extern "C" void kernel_launch(void* const* d_in, const int* in_sizes, int n_in,
                              void* d_out, int out_size, void* d_ws, size_t ws_size,
                              hipStream_t stream) {
    const float* x      = (const float*)d_in[0];
    const float* wq_idx = (const float*)d_in[1];
    const float* wk_idx = (const float*)d_in[2];
    const float* ww_idx = (const float*)d_in[3];
    const float* wq     = (const float*)d_in[4];
    const float* wk     = (const float*)d_in[5];
    const float* wv     = (const float*)d_in[6];
    const float* wo     = (const float*)d_in[7];
    float* out = (float*)d_out;
    char*  ws  = (char*)d_ws;

    size_t off = 0;
    auto carve = [&](size_t bytes) { size_t o = off; off = (off + bytes + 255) & ~(size_t)255; return o; };
    size_t oWqh = carve((size_t)QKV_COLS*DMODEL*2);
    size_t oWql = carve((size_t)QKV_COLS*DMODEL*2);
    size_t oWoh = carve((size_t)DMODEL*DMODEL*2);
    size_t oWol = carve((size_t)DMODEL*DMODEL*2);
    size_t oWi  = carve((size_t)DMODEL*IDX_COLS*4);
    size_t oXh  = carve((size_t)NQ*DMODEL*2);
    size_t oXl  = carve((size_t)NQ*DMODEL*2);
    size_t oY   = carve((size_t)NQ*QKV_COLS*4);
    size_t oP   = carve((size_t)NQ*IDX_COLS*8);
    size_t oIdx = carve((size_t)NQ*TOPK*4);
    size_t oCh  = carve((size_t)NQ*NH*DV*2);
    size_t oCl  = carve((size_t)NQ*NH*DV*2);
    size_t oKL  = off;

    // chunk region: one sortable u32 key per score
    int QC = NQ;
    while (QC > 32 && oKL + (size_t)QC*NSEQ*4 > ws_size) QC >>= 1;

    unsigned short* WqT_hi = (unsigned short*)(ws + oWqh);
    unsigned short* WqT_lo = (unsigned short*)(ws + oWql);
    unsigned short* WoT_hi = (unsigned short*)(ws + oWoh);
    unsigned short* WoT_lo = (unsigned short*)(ws + oWol);
    float*  Wi_cat = (float*)(ws + oWi);
    unsigned short* xhi = (unsigned short*)(ws + oXh);
    unsigned short* xlo = (unsigned short*)(ws + oXl);
    float*  Y      = (float*)(ws + oY);
    double* P      = (double*)(ws + oP);
    int*    IDX    = (int*)(ws + oIdx);
    unsigned short* ctx_hi = (unsigned short*)(ws + oCh);
    unsigned short* ctx_lo = (unsigned short*)(ws + oCl);
    unsigned int* K32 = (unsigned int*)(ws + oKL);

    int ncat = QKV_COLS*DMODEL + DMODEL*DMODEL + DMODEL*IDX_COLS;
    k_split<<<(NQ*DMODEL + 255)/256, 256, 0, stream>>>(x, xhi, xlo);
    k_concat<<<(ncat + 255)/256, 256, 0, stream>>>(wq_idx, wk_idx, ww_idx, wq, wk, wv, wo,
                                                   WqT_hi, WqT_lo, WoT_hi, WoT_lo, Wi_cat);
    k_gemm_mfma<<<dim3((QKV_COLS + 63)/64, NQ/128), 256, 0, stream>>>(xhi, xlo, WqT_hi, WqT_lo, Y, QKV_COLS, QKV_COLS);
    k_proj64<<<NQ/32, 256, 0, stream>>>(x, Wi_cat, P);
    for (int qs = 0; qs < NQ; qs += QC) {
        k_score_mfma<<<dim3(NSEQ/128, QC/32), 256, 0, stream>>>(P, K32, qs);
        k_topk<<<QC, 256, 0, stream>>>(K32, IDX, qs);
    }
    k_attn<<<NQ, 512, 0, stream>>>(Y, IDX, ctx_hi, ctx_lo);
    k_gemm_mfma<<<dim3(DMODEL/64, NQ/128), 256, 0, stream>>>(ctx_hi, ctx_lo, WoT_hi, WoT_lo, out, DMODEL, DMODEL);
}